// Round 7
// baseline (420.182 us; speedup 1.0000x reference)
//
#include <hip/hip_runtime.h>
#include <hip/hip_bf16.h>

#define BB 4
#define TT 1024
#define DM 1024
#define HH 16

typedef __attribute__((ext_vector_type(8))) short short8;
typedef __attribute__((ext_vector_type(4))) short short4v;
typedef __attribute__((ext_vector_type(4))) float f32x4;
typedef __hip_bfloat16 bf16;

__device__ __forceinline__ f32x4 mfma16(short8 a, short8 b, f32x4 c) {
  return __builtin_amdgcn_mfma_f32_16x16x32_bf16(a, b, c, 0, 0, 0);
}

// ---------------------------------------------------------------------------
// x fp32 -> bf16, 8 elems/thread. grid 2048.
// ---------------------------------------------------------------------------
__global__ __launch_bounds__(256) void xb_kernel(
    const float* __restrict__ x, bf16* __restrict__ xb) {
  const size_t i = ((size_t)blockIdx.x * 256 + threadIdx.x) * 8;
  bf16 tmp[8];
#pragma unroll
  for (int j = 0; j < 8; ++j) tmp[j] = __float2bfloat16(x[i + j]);
  *(short8*)(xb + i) = *(const short8*)tmp;
}

// ---------------------------------------------------------------------------
// W_{Q,K,V} fp32 [16][64 d][64 e] -> Wt bf16 [3][16][64 e][64 d] (transposed)
// grid (16 h, 3 m)
// ---------------------------------------------------------------------------
__global__ __launch_bounds__(256) void prep_w_kernel(
    const float* __restrict__ WQ, const float* __restrict__ WK,
    const float* __restrict__ WV, bf16* __restrict__ Wt) {
  __shared__ bf16 tl[64][72];
  const int h = blockIdx.x, m = blockIdx.y;
  const float* W = (m == 0 ? WQ : (m == 1 ? WK : WV)) + h * 4096;
  const int tid = threadIdx.x;
  const int r = tid >> 2, c = (tid & 3) * 16;
#pragma unroll
  for (int i = 0; i < 16; ++i)
    tl[r][c + i] = __float2bfloat16(W[r * 64 + c + i]);  // tl[d][e]
  __syncthreads();
  bf16* o = Wt + ((size_t)(m * 16 + h) * 64 + r) * 64 + c;  // [e=r][d=c..]
#pragma unroll
  for (int i = 0; i < 16; ++i) o[i] = tl[c + i][r];
}

// ---------------------------------------------------------------------------
// prep: posK fp32 [2047][64] -> bf16 [2048][64] (row 2047 zeroed)
// ---------------------------------------------------------------------------
__global__ __launch_bounds__(256) void prep_posk_kernel(
    const float* __restrict__ posK, bf16* __restrict__ posKbf) {
  const int idx = blockIdx.x * 256 + threadIdx.x;
  const int p = idx >> 6, d = idx & 63;
  const float v = (p < 2047) ? posK[(size_t)p * 64 + d] : 0.f;
  posKbf[idx] = __float2bfloat16(v);
}

// ---------------------------------------------------------------------------
// prep: WzT bf16 [n][k] = Wz fp32 [k][n]
// ---------------------------------------------------------------------------
__global__ __launch_bounds__(256) void trans_wz_kernel(
    const float* __restrict__ Wz, bf16* __restrict__ WzT) {
  __shared__ bf16 tile[64][72];
  const int k0 = blockIdx.y * 64, n0 = blockIdx.x * 64;
  const int tid = threadIdx.x;
  const int r = tid >> 2, c = (tid & 3) * 16;
  const float* s = Wz + (size_t)(k0 + r) * 1024 + n0 + c;
#pragma unroll
  for (int i = 0; i < 16; ++i) tile[r][c + i] = __float2bfloat16(s[i]);
  __syncthreads();
  const int n = tid >> 2;
  bf16* o = WzT + (size_t)(n0 + n) * 1024 + k0 + c;
#pragma unroll
  for (int i = 0; i < 16; ++i) o[i] = tile[c + i][n];
}

// ---------------------------------------------------------------------------
// transpose V: [bh][1024][64] bf16 -> Vt [bh][64][1024] bf16
// ---------------------------------------------------------------------------
__global__ __launch_bounds__(256) void trans_v_kernel(
    const bf16* __restrict__ src, bf16* __restrict__ dst) {
  __shared__ bf16 tile[64][72];
  const int bh = blockIdx.y, t0 = blockIdx.x * 64;
  const int tid = threadIdx.x;
  const int r = tid >> 2, c = (tid & 3) * 16;
  const bf16* s = src + ((size_t)bh * TT + t0 + r) * 64 + c;
  *(short8*)(&tile[r][c]) = *(const short8*)(s);
  *(short8*)(&tile[r][c + 8]) = *(const short8*)(s + 8);
  __syncthreads();
  const int d = tid >> 2;
  bf16* o = dst + ((size_t)bh * 64 + d) * TT + t0 + c;
#pragma unroll
  for (int i = 0; i < 16; ++i) o[i] = tile[c + i][d];
}

// ---------------------------------------------------------------------------
// QKV projection via MFMA. grid (16 ttiles, 64 bh), block 256 (4 waves).
// ---------------------------------------------------------------------------
__global__ __launch_bounds__(256) void qkv_mfma_kernel(
    const bf16* __restrict__ xb, const bf16* __restrict__ Wt,
    bf16* __restrict__ Qg, bf16* __restrict__ Kg, bf16* __restrict__ Vg) {
  __shared__ __align__(16) bf16 xs[64 * 72];
  const int bh = blockIdx.y;
  const int b = bh >> 4, h = bh & 15;
  const int t0 = blockIdx.x * 64;
  const int tid = threadIdx.x;
  const int w = tid >> 6, lane = tid & 63, l15 = lane & 15, hi = lane >> 4;

  {
    const int r = tid >> 2, c = (tid & 3) * 16;
    const bf16* src = xb + ((size_t)b * TT + t0 + r) * DM + h * 64 + c;
    *(short8*)(xs + r * 72 + c) = *(const short8*)(src);
    *(short8*)(xs + r * 72 + c + 8) = *(const short8*)(src + 8);
  }
  __syncthreads();

  f32x4 aQ[4] = {{0.f, 0.f, 0.f, 0.f}, {0.f, 0.f, 0.f, 0.f},
                 {0.f, 0.f, 0.f, 0.f}, {0.f, 0.f, 0.f, 0.f}};
  f32x4 aK[4] = {{0.f, 0.f, 0.f, 0.f}, {0.f, 0.f, 0.f, 0.f},
                 {0.f, 0.f, 0.f, 0.f}, {0.f, 0.f, 0.f, 0.f}};
  f32x4 aV[4] = {{0.f, 0.f, 0.f, 0.f}, {0.f, 0.f, 0.f, 0.f},
                 {0.f, 0.f, 0.f, 0.f}, {0.f, 0.f, 0.f, 0.f}};
  const bf16* WtQ = Wt + (size_t)h * 4096;
  const bf16* WtK = Wt + (size_t)(16 + h) * 4096;
  const bf16* WtV = Wt + (size_t)(32 + h) * 4096;
#pragma unroll
  for (int kc = 0; kc < 2; ++kc) {
    const short8 a =
        *(const short8*)(xs + (w * 16 + l15) * 72 + kc * 32 + hi * 8);
#pragma unroll
    for (int nt = 0; nt < 4; ++nt) {
      const size_t wo = (size_t)(nt * 16 + l15) * 64 + kc * 32 + hi * 8;
      aQ[nt] = mfma16(a, *(const short8*)(WtQ + wo), aQ[nt]);
      aK[nt] = mfma16(a, *(const short8*)(WtK + wo), aK[nt]);
      aV[nt] = mfma16(a, *(const short8*)(WtV + wo), aV[nt]);
    }
  }
  const int t = t0 + w * 16 + hi * 4;
#pragma unroll
  for (int nt = 0; nt < 4; ++nt) {
#pragma unroll
    for (int j = 0; j < 4; ++j) {
      const size_t o = ((size_t)bh * TT + t + j) * 64 + nt * 16 + l15;
      Qg[o] = __float2bfloat16(aQ[nt][j]);
      Kg[o] = __float2bfloat16(aK[nt][j]);
      Vg[o] = __float2bfloat16(aV[nt][j]);
    }
  }
}

// ---------------------------------------------------------------------------
// Fused score kernel v3: 2-stage register software pipeline.
// All global operands (K b-frags, Vt b-frags, pos, mask) for tile it+1 are
// issued at the top of iteration it; tile it computes purely from registers.
// grid (16 qtiles, 64 bh), block 256 (4 waves).
// ---------------------------------------------------------------------------
#define QP8_S 2052
#define PSM_S 72

__global__ __launch_bounds__(256, 4) void score_pv_kernel(
    const bf16* __restrict__ Qb,
    const bf16* __restrict__ Kb,
    const bf16* __restrict__ posKbf,
    const bf16* __restrict__ Vt,
    const float* __restrict__ maskp,
    const int* __restrict__ pos,
    bf16* __restrict__ Pws,        // [256 qlocal][64 bh][1024 k]
    float* __restrict__ l_ws,      // [64 bh][1024 q]
    float* __restrict__ ctxU,      // [b][t][1024] fp32 unnormalized
    int slab) {
  __shared__ __align__(16) unsigned char QPsh[16 * QP8_S];  // 32832 B
  __shared__ __align__(16) bf16 Psm[2][16 * PSM_S];         // 4608 B
  __shared__ float lred[4][16];                             // 256 B

  const int bh = blockIdx.y;
  const int qt = blockIdx.x;
  const int qlocal0 = qt * 16;
  const int qg0 = slab * 256 + qlocal0;
  const int tid = threadIdx.x;
  const int w = tid >> 6;
  const int lane = tid & 63;
  const int l15 = lane & 15;
  const int hi = lane >> 4;

  const bf16* Qrow = Qb + ((size_t)bh * TT + qg0 + l15) * 64 + hi * 8;
  const short8 aq0 = *(const short8*)(Qrow);
  const short8 aq1 = *(const short8*)(Qrow + 32);

  // ---- QP phase: wave w covers p-tiles w*32 .. w*32+31; store fp8
  for (int i = 0; i < 32; ++i) {
    const int pt = w * 32 + i;
    const bf16* Kp = posKbf + ((size_t)(pt * 16 + l15)) * 64 + hi * 8;
    const short8 b0 = *(const short8*)(Kp);
    const short8 b1 = *(const short8*)(Kp + 32);
    f32x4 acc = {0.f, 0.f, 0.f, 0.f};
    acc = mfma16(aq0, b0, acc);
    acc = mfma16(aq1, b1, acc);
    const int p01 = __builtin_amdgcn_cvt_pk_fp8_f32(acc[0], acc[1], 0, false);
    const int p23 = __builtin_amdgcn_cvt_pk_fp8_f32(acc[2], acc[3], 0, false);
    const int off = pt * 16 + l15;
    QPsh[(hi * 4 + 0) * QP8_S + off] = (unsigned char)(p01 & 0xff);
    QPsh[(hi * 4 + 1) * QP8_S + off] = (unsigned char)((p01 >> 8) & 0xff);
    QPsh[(hi * 4 + 2) * QP8_S + off] = (unsigned char)(p23 & 0xff);
    QPsh[(hi * 4 + 3) * QP8_S + off] = (unsigned char)((p23 >> 8) & 0xff);
  }
  __syncthreads();

  // wave w owns PV output d-tile [w*16, w*16+16)
  f32x4 acc_pv = {0.f, 0.f, 0.f, 0.f};
  float lp[4] = {0.f, 0.f, 0.f, 0.f};
  const int kk = w * 16 + l15;
  const bf16* Kbh = Kb + (size_t)bh * TT * 64;
  const bf16* Vtrow = Vt + ((size_t)bh * 64 + w * 16 + l15) * TT;

  // prologue: stage tile 0 operands in registers
  short8 nb0 = *(const short8*)(Kbh + (size_t)kk * 64 + hi * 8);
  short8 nb1 = *(const short8*)(Kbh + (size_t)kk * 64 + 32 + hi * 8);
  short8 nv0 = *(const short8*)(Vtrow + hi * 8);
  short8 nv1 = *(const short8*)(Vtrow + 32 + hi * 8);
  int npos[4];
  float nmask[4];
#pragma unroll
  for (int j = 0; j < 4; ++j) {
    const size_t go = (size_t)(qg0 + hi * 4 + j) * TT + kk;
    npos[j] = pos[go];
    nmask[j] = maskp[go];
  }

  for (int it = 0; it < 16; ++it) {
    const int k0 = it * 64;
    bf16* PsmC = &Psm[it & 1][0];
    // retire staged regs for this tile
    const short8 cb0 = nb0, cb1 = nb1, cv0 = nv0, cv1 = nv1;
    int cpos[4];
    float cmask[4];
#pragma unroll
    for (int j = 0; j < 4; ++j) {
      cpos[j] = npos[j];
      cmask[j] = nmask[j];
    }
    // issue next tile's loads (clamped wrap on last iter; harmless re-read)
    {
      const int k0n = ((it + 1) & 15) * 64;
      nb0 = *(const short8*)(Kbh + (size_t)(k0n + kk) * 64 + hi * 8);
      nb1 = *(const short8*)(Kbh + (size_t)(k0n + kk) * 64 + 32 + hi * 8);
      nv0 = *(const short8*)(Vtrow + k0n + hi * 8);
      nv1 = *(const short8*)(Vtrow + k0n + 32 + hi * 8);
#pragma unroll
      for (int j = 0; j < 4; ++j) {
        const size_t gon = (size_t)(qg0 + hi * 4 + j) * TT + k0n + kk;
        npos[j] = pos[gon];
        nmask[j] = maskp[gon];
      }
    }
    // content scores from registers
    f32x4 s = {0.f, 0.f, 0.f, 0.f};
    s = mfma16(aq0, cb0, s);
    s = mfma16(aq1, cb1, s);
    // + QP[pos] (fp8 LDS gather) + mask, *0.125, exp -> Psm[cur]
#pragma unroll
    for (int j = 0; j < 4; ++j) {
      const int q = hi * 4 + j;
      const float qp =
          __builtin_amdgcn_cvt_f32_fp8((int)QPsh[q * QP8_S + cpos[j]], 0);
      float sv = s[j] + qp;
      sv = (sv + cmask[j]) * 0.125f;
      const float pe = __expf(sv);
      lp[j] += pe;
      PsmC[q * PSM_S + kk] = __float2bfloat16(pe);
    }
    __syncthreads();
    // store P tile to global (unnormalized), coalesced via LDS
    {
      const int r = tid >> 4, c = (tid & 15) * 4;
      *(short4v*)(Pws + ((size_t)(qlocal0 + r) * 64 + bh) * TT + k0 + c) =
          *(const short4v*)(PsmC + r * PSM_S + c);
    }
    // PV MFMAs from registers (Vt) + LDS (P)
    {
      const short8 pa0 = *(const short8*)(PsmC + l15 * PSM_S + hi * 8);
      acc_pv = mfma16(pa0, cv0, acc_pv);
      const short8 pa1 = *(const short8*)(PsmC + l15 * PSM_S + 32 + hi * 8);
      acc_pv = mfma16(pa1, cv1, acc_pv);
    }
    // no trailing barrier: next iter writes the other Psm buffer
  }

  // l row-sums: waves hold disjoint k-slices -> sum across lanes then waves
#pragma unroll
  for (int j = 0; j < 4; ++j) {
    float v = lp[j];
    v += __shfl_xor(v, 1);
    v += __shfl_xor(v, 2);
    v += __shfl_xor(v, 4);
    v += __shfl_xor(v, 8);
    if (l15 == 0) lred[w][hi * 4 + j] = v;
  }
  __syncthreads();
  if (tid < 16) {
    const float l = lred[0][tid] + lred[1][tid] + lred[2][tid] + lred[3][tid];
    l_ws[(size_t)bh * TT + qg0 + tid] = l;
  }
  {
    const int b = bh >> 4, h = bh & 15;
#pragma unroll
    for (int j = 0; j < 4; ++j) {
      const int q = hi * 4 + j;
      ctxU[((size_t)b * TT + qg0 + q) * DM + h * 64 + w * 16 + l15] = acc_pv[j];
    }
  }
}

// ---------------------------------------------------------------------------
// PV partial kernel (k-split x4): grid (256 q, 4 ks), block 256.
// ---------------------------------------------------------------------------
#define PVT_S 72
__global__ __launch_bounds__(256) void pv_part_kernel(
    const bf16* __restrict__ Pws,
    const float* __restrict__ posV,
    const int* __restrict__ pos,
    float* __restrict__ PP,   // [4][256][64][64] fp32
    int slab) {
  __shared__ __align__(16) bf16 PVt[2][64 * PVT_S];
  __shared__ unsigned short possh[256];

  const int qlocal = blockIdx.x;
  const int q = slab * 256 + qlocal;
  const int ks = blockIdx.y;
  const int kbase = ks * 256;
  const int tid = threadIdx.x;
  const int w = tid >> 6, lane = tid & 63, l15 = lane & 15, hi = lane >> 4;

  possh[tid] = (unsigned short)pos[(size_t)q * TT + kbase + tid];
  __syncthreads();

  f32x4 acc[4] = {{0.f, 0.f, 0.f, 0.f}, {0.f, 0.f, 0.f, 0.f},
                  {0.f, 0.f, 0.f, 0.f}, {0.f, 0.f, 0.f, 0.f}};
  const bf16* Prow = Pws + ((size_t)qlocal * 64 + w * 16 + l15) * TT;

  for (int it = 0; it < 4; ++it) {
    const int k0 = kbase + it * 64;
    bf16* pvt = &PVt[it & 1][0];
    {
      const int kr = lane;
      const int dc = w * 16;
      const int p = possh[it * 64 + kr];
      const float* src = posV + (size_t)p * 64 + dc;
#pragma unroll
      for (int ii = 0; ii < 16; ii += 4) {
        const f32x4 v = *(const f32x4*)(src + ii);
        pvt[(dc + ii + 0) * PVT_S + kr] = __float2bfloat16(v[0]);
        pvt[(dc + ii + 1) * PVT_S + kr] = __float2bfloat16(v[1]);
        pvt[(dc + ii + 2) * PVT_S + kr] = __float2bfloat16(v[2]);
        pvt[(dc + ii + 3) * PVT_S + kr] = __float2bfloat16(v[3]);
      }
    }
    __syncthreads();
#pragma unroll
    for (int kc = 0; kc < 2; ++kc) {
      const short8 a = *(const short8*)(Prow + k0 + kc * 32 + hi * 8);
#pragma unroll
      for (int nt = 0; nt < 4; ++nt) {
        const short8 bv =
            *(const short8*)(pvt + (nt * 16 + l15) * PVT_S + kc * 32 + hi * 8);
        acc[nt] = mfma16(a, bv, acc[nt]);
      }
    }
  }

  const int bh0 = w * 16 + hi * 4;
#pragma unroll
  for (int j = 0; j < 4; ++j) {
    const int bh = bh0 + j;
    float* o = PP + (((size_t)ks * 256 + qlocal) * 64 + bh) * 64;
#pragma unroll
    for (int nt = 0; nt < 4; ++nt) o[nt * 16 + l15] = acc[nt][j];
  }
}

// ---------------------------------------------------------------------------
// Normalize: ctxB = (ctxU + sum_ks PP) / l. grid 1024, block 256.
// ---------------------------------------------------------------------------
__global__ __launch_bounds__(256) void norm_kernel(
    const float* __restrict__ PP,
    const float* __restrict__ ctxU,
    const float* __restrict__ l_ws,
    bf16* __restrict__ ctxB,
    int slab) {
  const int i4 = blockIdx.x * 256 + threadIdx.x;  // 0..262143
  const int e0 = i4 * 4;
  const int dm = e0 & 1023;
  const int qlocal = (e0 >> 10) & 255;
  const int b = e0 >> 18;
  const int h = dm >> 6, d0 = dm & 63;
  const int bh = b * 16 + h;
  const int q = slab * 256 + qlocal;

  f32x4 v = *(const f32x4*)(ctxU + ((size_t)b * TT + q) * DM + dm);
#pragma unroll
  for (int ks = 0; ks < 4; ++ks)
    v += *(const f32x4*)(PP + (((size_t)ks * 256 + qlocal) * 64 + bh) * 64 + d0);
  const float invl = 1.0f / l_ws[(size_t)bh * TT + q];
  bf16 o[4];
#pragma unroll
  for (int j = 0; j < 4; ++j) o[j] = __float2bfloat16(v[j] * invl);
  *(short4v*)(ctxB + ((size_t)b * TT + q) * DM + dm) = *(const short4v*)o;
}

// ---------------------------------------------------------------------------
// Output projection: 128x128 LDS-tiled MFMA GEMM, BK=64, 4 waves (2x2).
// grid (8 nblk, 32 mblk), block 256.
// ---------------------------------------------------------------------------
__global__ __launch_bounds__(256) void outproj_mfma_kernel(
    const bf16* __restrict__ A,   // [4096][1024] bf16
    const bf16* __restrict__ Bt,  // [1024 n][1024 k] bf16
    float* __restrict__ C) {
  __shared__ __align__(16) bf16 As[128 * 72];
  __shared__ __align__(16) bf16 Bs[128 * 72];
  const int n0 = blockIdx.x * 128;
  const int m0 = blockIdx.y * 128;
  const int tid = threadIdx.x;
  const int w = tid >> 6, lane = tid & 63, l15 = lane & 15, hi = lane >> 4;
  const int wm = w >> 1, wn = w & 1;

  f32x4 acc[4][4];
#pragma unroll
  for (int i = 0; i < 4; ++i)
#pragma unroll
    for (int j = 0; j < 4; ++j) acc[i][j] = (f32x4){0.f, 0.f, 0.f, 0.f};

  const int sr = tid >> 1, sc = (tid & 1) * 32;
  for (int k0 = 0; k0 < 1024; k0 += 64) {
    __syncthreads();
    {
      const bf16* as = A + (size_t)(m0 + sr) * 1024 + k0 + sc;
      const bf16* bs = Bt + (size_t)(n0 + sr) * 1024 + k0 + sc;
#pragma unroll
      for (int ii = 0; ii < 32; ii += 8) {
        *(short8*)(As + sr * 72 + sc + ii) = *(const short8*)(as + ii);
        *(short8*)(Bs + sr * 72 + sc + ii) = *(const short8*)(bs + ii);
      }
    }
    __syncthreads();
#pragma unroll
    for (int kc = 0; kc < 2; ++kc) {
      short8 a[4], b[4];
#pragma unroll
      for (int i = 0; i < 4; ++i)
        a[i] = *(const short8*)(As + (wm * 64 + i * 16 + l15) * 72 + kc * 32 +
                                hi * 8);
#pragma unroll
      for (int j = 0; j < 4; ++j)
        b[j] = *(const short8*)(Bs + (wn * 64 + j * 16 + l15) * 72 + kc * 32 +
                                hi * 8);
#pragma unroll
      for (int i = 0; i < 4; ++i)
#pragma unroll
        for (int j = 0; j < 4; ++j) acc[i][j] = mfma16(a[i], b[j], acc[i][j]);
    }
  }
#pragma unroll
  for (int i = 0; i < 4; ++i) {
#pragma unroll
    for (int jj = 0; jj < 4; ++jj) {
      const size_t row = (size_t)(m0 + wm * 64 + i * 16 + hi * 4 + jj) * 1024;
#pragma unroll
      for (int j = 0; j < 4; ++j)
        C[row + n0 + wn * 64 + j * 16 + l15] = acc[i][j][jj];
    }
  }
}

// ---------------------------------------------------------------------------
extern "C" void kernel_launch(void* const* d_in, const int* in_sizes, int n_in,
                              void* d_out, int out_size, void* d_ws,
                              size_t ws_size, hipStream_t stream) {
  const float* x = (const float*)d_in[0];
  const float* WQ = (const float*)d_in[1];
  const float* WK = (const float*)d_in[2];
  const float* WV = (const float*)d_in[3];
  const float* WZ = (const float*)d_in[4];
  const float* posK = (const float*)d_in[5];
  const float* posV = (const float*)d_in[6];
  const float* maskp = (const float*)d_in[7];
  const int* pos = (const int*)d_in[8];
  float* out = (float*)d_out;

  char* p = (char*)d_ws;
  bf16* Qb = (bf16*)p;        p += (size_t)64 * 1024 * 64 * 2;   // 8 MB
  bf16* Kb = (bf16*)p;        p += (size_t)64 * 1024 * 64 * 2;   // 8 MB
  bf16* Vb = (bf16*)p;        p += (size_t)64 * 1024 * 64 * 2;   // 8 MB
  bf16* Vt = (bf16*)p;        p += (size_t)64 * 64 * 1024 * 2;   // 8 MB
  bf16* posKbf = (bf16*)p;    p += (size_t)2048 * 64 * 2;        // 256 KB
  bf16* WzT = (bf16*)p;       p += (size_t)1024 * 1024 * 2;      // 2 MB
  bf16* Pws = (bf16*)p;       p += (size_t)256 * 64 * 1024 * 2;  // 32 MB
  float* l_ws = (float*)p;    p += (size_t)64 * 1024 * 4;        // 256 KB
  float* ctxU = (float*)p;    p += (size_t)4 * 1024 * 1024 * 4;  // 16 MB
  bf16* ctxB = (bf16*)p;      p += (size_t)4 * 1024 * 1024 * 2;  // 8 MB
  float* PP = (float*)p;      p += (size_t)4 * 256 * 64 * 64 * 4; // 16 MB

  // Aliases (dead-range reuse, safe under stream ordering):
  bf16* xb = (bf16*)ctxU;  // xb dead after qkv; ctxU written later
  bf16* Wt = ctxB;         // Wt dead after qkv; ctxB written later

  xb_kernel<<<2048, 256, 0, stream>>>(x, xb);
  prep_w_kernel<<<dim3(16, 3), 256, 0, stream>>>(WQ, WK, WV, Wt);
  prep_posk_kernel<<<512, 256, 0, stream>>>(posK, posKbf);
  trans_wz_kernel<<<dim3(16, 16), 256, 0, stream>>>(WZ, WzT);
  qkv_mfma_kernel<<<dim3(16, 64), 256, 0, stream>>>(xb, Wt, Qb, Kb, Vb);
  trans_v_kernel<<<dim3(16, 64), 256, 0, stream>>>(Vb, Vt);

  for (int slab = 0; slab < 4; ++slab) {
    score_pv_kernel<<<dim3(16, 64), 256, 0, stream>>>(
        Qb, Kb, posKbf, Vt, maskp, pos, Pws, l_ws, ctxU, slab);
    pv_part_kernel<<<dim3(256, 4), 256, 0, stream>>>(Pws, posV, pos, PP, slab);
    norm_kernel<<<1024, 256, 0, stream>>>(PP, ctxU, l_ws, ctxB, slab);
  }
  outproj_mfma_kernel<<<dim3(8, 32), 256, 0, stream>>>(ctxB, WzT, out);
}

// Round 8
// 418.243 us; speedup vs baseline: 1.0046x; 1.0046x over previous
//
#include <hip/hip_runtime.h>
#include <hip/hip_bf16.h>

#define BB 4
#define TT 1024
#define DM 1024
#define HH 16

typedef __attribute__((ext_vector_type(8))) short short8;
typedef __attribute__((ext_vector_type(4))) short short4v;
typedef __attribute__((ext_vector_type(4))) float f32x4;
typedef __hip_bfloat16 bf16;

__device__ __forceinline__ f32x4 mfma16(short8 a, short8 b, f32x4 c) {
  return __builtin_amdgcn_mfma_f32_16x16x32_bf16(a, b, c, 0, 0, 0);
}

// ---------------------------------------------------------------------------
// x fp32 -> bf16, 8 elems/thread. grid 2048.
// ---------------------------------------------------------------------------
__global__ __launch_bounds__(256) void xb_kernel(
    const float* __restrict__ x, bf16* __restrict__ xb) {
  const size_t i = ((size_t)blockIdx.x * 256 + threadIdx.x) * 8;
  bf16 tmp[8];
#pragma unroll
  for (int j = 0; j < 8; ++j) tmp[j] = __float2bfloat16(x[i + j]);
  *(short8*)(xb + i) = *(const short8*)tmp;
}

// ---------------------------------------------------------------------------
// W_{Q,K,V} fp32 [16][64 d][64 e] -> Wt bf16 [3][16][64 e][64 d] (transposed)
// grid (16 h, 3 m)
// ---------------------------------------------------------------------------
__global__ __launch_bounds__(256) void prep_w_kernel(
    const float* __restrict__ WQ, const float* __restrict__ WK,
    const float* __restrict__ WV, bf16* __restrict__ Wt) {
  __shared__ bf16 tl[64][72];
  const int h = blockIdx.x, m = blockIdx.y;
  const float* W = (m == 0 ? WQ : (m == 1 ? WK : WV)) + h * 4096;
  const int tid = threadIdx.x;
  const int r = tid >> 2, c = (tid & 3) * 16;
#pragma unroll
  for (int i = 0; i < 16; ++i)
    tl[r][c + i] = __float2bfloat16(W[r * 64 + c + i]);  // tl[d][e]
  __syncthreads();
  bf16* o = Wt + ((size_t)(m * 16 + h) * 64 + r) * 64 + c;  // [e=r][d=c..]
#pragma unroll
  for (int i = 0; i < 16; ++i) o[i] = tl[c + i][r];
}

// ---------------------------------------------------------------------------
// prep: posK fp32 [2047][64] -> bf16 [2048][64] (row 2047 zeroed)
// ---------------------------------------------------------------------------
__global__ __launch_bounds__(256) void prep_posk_kernel(
    const float* __restrict__ posK, bf16* __restrict__ posKbf) {
  const int idx = blockIdx.x * 256 + threadIdx.x;
  const int p = idx >> 6, d = idx & 63;
  const float v = (p < 2047) ? posK[(size_t)p * 64 + d] : 0.f;
  posKbf[idx] = __float2bfloat16(v);
}

// ---------------------------------------------------------------------------
// prep: WzT bf16 [n][k] = Wz fp32 [k][n]
// ---------------------------------------------------------------------------
__global__ __launch_bounds__(256) void trans_wz_kernel(
    const float* __restrict__ Wz, bf16* __restrict__ WzT) {
  __shared__ bf16 tile[64][72];
  const int k0 = blockIdx.y * 64, n0 = blockIdx.x * 64;
  const int tid = threadIdx.x;
  const int r = tid >> 2, c = (tid & 3) * 16;
  const float* s = Wz + (size_t)(k0 + r) * 1024 + n0 + c;
#pragma unroll
  for (int i = 0; i < 16; ++i) tile[r][c + i] = __float2bfloat16(s[i]);
  __syncthreads();
  const int n = tid >> 2;
  bf16* o = WzT + (size_t)(n0 + n) * 1024 + k0 + c;
#pragma unroll
  for (int i = 0; i < 16; ++i) o[i] = tile[c + i][n];
}

// ---------------------------------------------------------------------------
// transpose V: [bh][1024][64] bf16 -> Vt [bh][64][1024] bf16
// ---------------------------------------------------------------------------
__global__ __launch_bounds__(256) void trans_v_kernel(
    const bf16* __restrict__ src, bf16* __restrict__ dst) {
  __shared__ bf16 tile[64][72];
  const int bh = blockIdx.y, t0 = blockIdx.x * 64;
  const int tid = threadIdx.x;
  const int r = tid >> 2, c = (tid & 3) * 16;
  const bf16* s = src + ((size_t)bh * TT + t0 + r) * 64 + c;
  *(short8*)(&tile[r][c]) = *(const short8*)(s);
  *(short8*)(&tile[r][c + 8]) = *(const short8*)(s + 8);
  __syncthreads();
  const int d = tid >> 2;
  bf16* o = dst + ((size_t)bh * 64 + d) * TT + t0 + c;
#pragma unroll
  for (int i = 0; i < 16; ++i) o[i] = tile[c + i][d];
}

// ---------------------------------------------------------------------------
// QKV projection via MFMA. grid (16 ttiles, 64 bh), block 256 (4 waves).
// ---------------------------------------------------------------------------
__global__ __launch_bounds__(256) void qkv_mfma_kernel(
    const bf16* __restrict__ xb, const bf16* __restrict__ Wt,
    bf16* __restrict__ Qg, bf16* __restrict__ Kg, bf16* __restrict__ Vg) {
  __shared__ __align__(16) bf16 xs[64 * 72];
  const int bh = blockIdx.y;
  const int b = bh >> 4, h = bh & 15;
  const int t0 = blockIdx.x * 64;
  const int tid = threadIdx.x;
  const int w = tid >> 6, lane = tid & 63, l15 = lane & 15, hi = lane >> 4;

  {
    const int r = tid >> 2, c = (tid & 3) * 16;
    const bf16* src = xb + ((size_t)b * TT + t0 + r) * DM + h * 64 + c;
    *(short8*)(xs + r * 72 + c) = *(const short8*)(src);
    *(short8*)(xs + r * 72 + c + 8) = *(const short8*)(src + 8);
  }
  __syncthreads();

  f32x4 aQ[4] = {{0.f, 0.f, 0.f, 0.f}, {0.f, 0.f, 0.f, 0.f},
                 {0.f, 0.f, 0.f, 0.f}, {0.f, 0.f, 0.f, 0.f}};
  f32x4 aK[4] = {{0.f, 0.f, 0.f, 0.f}, {0.f, 0.f, 0.f, 0.f},
                 {0.f, 0.f, 0.f, 0.f}, {0.f, 0.f, 0.f, 0.f}};
  f32x4 aV[4] = {{0.f, 0.f, 0.f, 0.f}, {0.f, 0.f, 0.f, 0.f},
                 {0.f, 0.f, 0.f, 0.f}, {0.f, 0.f, 0.f, 0.f}};
  const bf16* WtQ = Wt + (size_t)h * 4096;
  const bf16* WtK = Wt + (size_t)(16 + h) * 4096;
  const bf16* WtV = Wt + (size_t)(32 + h) * 4096;
#pragma unroll
  for (int kc = 0; kc < 2; ++kc) {
    const short8 a =
        *(const short8*)(xs + (w * 16 + l15) * 72 + kc * 32 + hi * 8);
#pragma unroll
    for (int nt = 0; nt < 4; ++nt) {
      const size_t wo = (size_t)(nt * 16 + l15) * 64 + kc * 32 + hi * 8;
      aQ[nt] = mfma16(a, *(const short8*)(WtQ + wo), aQ[nt]);
      aK[nt] = mfma16(a, *(const short8*)(WtK + wo), aK[nt]);
      aV[nt] = mfma16(a, *(const short8*)(WtV + wo), aV[nt]);
    }
  }
  const int t = t0 + w * 16 + hi * 4;
#pragma unroll
  for (int nt = 0; nt < 4; ++nt) {
#pragma unroll
    for (int j = 0; j < 4; ++j) {
      const size_t o = ((size_t)bh * TT + t + j) * 64 + nt * 16 + l15;
      Qg[o] = __float2bfloat16(aQ[nt][j]);
      Kg[o] = __float2bfloat16(aK[nt][j]);
      Vg[o] = __float2bfloat16(aV[nt][j]);
    }
  }
}

// ---------------------------------------------------------------------------
// Fused score kernel v4:
//  - grid swapped to (64 bh, 16 qt): same-bh blocks are stride-64 apart
//    (64 % 8 == 0) -> all 16 qt of one bh map to ONE XCD -> K/Vt L2-resident
//    (2 MB/XCD working set vs 16 MB before).
//  - QP phase 2-stage register pipeline (was serial load->MFMA).
//  - k-loop 2-stage register pipeline (kept from v3).
// grid (64 bh, 16 qtiles), block 256 (4 waves).
// ---------------------------------------------------------------------------
#define QP8_S 2052
#define PSM_S 72

__global__ __launch_bounds__(256, 4) void score_pv_kernel(
    const bf16* __restrict__ Qb,
    const bf16* __restrict__ Kb,
    const bf16* __restrict__ posKbf,
    const bf16* __restrict__ Vt,
    const float* __restrict__ maskp,
    const int* __restrict__ pos,
    bf16* __restrict__ Pws,        // [256 qlocal][64 bh][1024 k]
    float* __restrict__ l_ws,      // [64 bh][1024 q]
    float* __restrict__ ctxU,      // [b][t][1024] fp32 unnormalized
    int slab) {
  __shared__ __align__(16) unsigned char QPsh[16 * QP8_S];  // 32832 B
  __shared__ __align__(16) bf16 Psm[2][16 * PSM_S];         // 4608 B
  __shared__ float lred[4][16];                             // 256 B

  const int bh = blockIdx.x;   // swapped: bh on x
  const int qt = blockIdx.y;   // qt on y
  const int qlocal0 = qt * 16;
  const int qg0 = slab * 256 + qlocal0;
  const int tid = threadIdx.x;
  const int w = tid >> 6;
  const int lane = tid & 63;
  const int l15 = lane & 15;
  const int hi = lane >> 4;

  const bf16* Qrow = Qb + ((size_t)bh * TT + qg0 + l15) * 64 + hi * 8;
  const short8 aq0 = *(const short8*)(Qrow);
  const short8 aq1 = *(const short8*)(Qrow + 32);

  // ---- QP phase: wave w covers p-tiles w*32 .. w*32+31; 2-stage pipeline
  {
    const bf16* Kp0 = posKbf + ((size_t)(w * 32 * 16 + l15)) * 64 + hi * 8;
    short8 qb0 = *(const short8*)(Kp0);
    short8 qb1 = *(const short8*)(Kp0 + 32);
    for (int i = 0; i < 32; ++i) {
      const int pt = w * 32 + i;
      const short8 cb0 = qb0, cb1 = qb1;
      {
        const int ptn = w * 32 + ((i + 1) & 31);
        const bf16* Kpn = posKbf + ((size_t)(ptn * 16 + l15)) * 64 + hi * 8;
        qb0 = *(const short8*)(Kpn);
        qb1 = *(const short8*)(Kpn + 32);
      }
      f32x4 acc = {0.f, 0.f, 0.f, 0.f};
      acc = mfma16(aq0, cb0, acc);
      acc = mfma16(aq1, cb1, acc);
      const int p01 = __builtin_amdgcn_cvt_pk_fp8_f32(acc[0], acc[1], 0, false);
      const int p23 = __builtin_amdgcn_cvt_pk_fp8_f32(acc[2], acc[3], 0, false);
      const int off = pt * 16 + l15;
      QPsh[(hi * 4 + 0) * QP8_S + off] = (unsigned char)(p01 & 0xff);
      QPsh[(hi * 4 + 1) * QP8_S + off] = (unsigned char)((p01 >> 8) & 0xff);
      QPsh[(hi * 4 + 2) * QP8_S + off] = (unsigned char)(p23 & 0xff);
      QPsh[(hi * 4 + 3) * QP8_S + off] = (unsigned char)((p23 >> 8) & 0xff);
    }
  }
  __syncthreads();

  // wave w owns PV output d-tile [w*16, w*16+16)
  f32x4 acc_pv = {0.f, 0.f, 0.f, 0.f};
  float lp[4] = {0.f, 0.f, 0.f, 0.f};
  const int kk = w * 16 + l15;
  const bf16* Kbh = Kb + (size_t)bh * TT * 64;
  const bf16* Vtrow = Vt + ((size_t)bh * 64 + w * 16 + l15) * TT;

  // prologue: stage tile 0 operands in registers
  short8 nb0 = *(const short8*)(Kbh + (size_t)kk * 64 + hi * 8);
  short8 nb1 = *(const short8*)(Kbh + (size_t)kk * 64 + 32 + hi * 8);
  short8 nv0 = *(const short8*)(Vtrow + hi * 8);
  short8 nv1 = *(const short8*)(Vtrow + 32 + hi * 8);
  int npos[4];
  float nmask[4];
#pragma unroll
  for (int j = 0; j < 4; ++j) {
    const size_t go = (size_t)(qg0 + hi * 4 + j) * TT + kk;
    npos[j] = pos[go];
    nmask[j] = maskp[go];
  }

  for (int it = 0; it < 16; ++it) {
    const int k0 = it * 64;
    bf16* PsmC = &Psm[it & 1][0];
    const short8 cb0 = nb0, cb1 = nb1, cv0 = nv0, cv1 = nv1;
    int cpos[4];
    float cmask[4];
#pragma unroll
    for (int j = 0; j < 4; ++j) {
      cpos[j] = npos[j];
      cmask[j] = nmask[j];
    }
    {
      const int k0n = ((it + 1) & 15) * 64;
      nb0 = *(const short8*)(Kbh + (size_t)(k0n + kk) * 64 + hi * 8);
      nb1 = *(const short8*)(Kbh + (size_t)(k0n + kk) * 64 + 32 + hi * 8);
      nv0 = *(const short8*)(Vtrow + k0n + hi * 8);
      nv1 = *(const short8*)(Vtrow + k0n + 32 + hi * 8);
#pragma unroll
      for (int j = 0; j < 4; ++j) {
        const size_t gon = (size_t)(qg0 + hi * 4 + j) * TT + k0n + kk;
        npos[j] = pos[gon];
        nmask[j] = maskp[gon];
      }
    }
    // content scores from registers
    f32x4 s = {0.f, 0.f, 0.f, 0.f};
    s = mfma16(aq0, cb0, s);
    s = mfma16(aq1, cb1, s);
    // + QP[pos] (fp8 LDS gather) + mask, *0.125, exp -> Psm[cur]
#pragma unroll
    for (int j = 0; j < 4; ++j) {
      const int q = hi * 4 + j;
      const float qp =
          __builtin_amdgcn_cvt_f32_fp8((int)QPsh[q * QP8_S + cpos[j]], 0);
      float sv = s[j] + qp;
      sv = (sv + cmask[j]) * 0.125f;
      const float pe = __expf(sv);
      lp[j] += pe;
      PsmC[q * PSM_S + kk] = __float2bfloat16(pe);
    }
    __syncthreads();
    // store P tile to global (unnormalized), coalesced via LDS
    {
      const int r = tid >> 4, c = (tid & 15) * 4;
      *(short4v*)(Pws + ((size_t)(qlocal0 + r) * 64 + bh) * TT + k0 + c) =
          *(const short4v*)(PsmC + r * PSM_S + c);
    }
    // PV MFMAs from registers (Vt) + LDS (P)
    {
      const short8 pa0 = *(const short8*)(PsmC + l15 * PSM_S + hi * 8);
      acc_pv = mfma16(pa0, cv0, acc_pv);
      const short8 pa1 = *(const short8*)(PsmC + l15 * PSM_S + 32 + hi * 8);
      acc_pv = mfma16(pa1, cv1, acc_pv);
    }
  }

  // l row-sums
#pragma unroll
  for (int j = 0; j < 4; ++j) {
    float v = lp[j];
    v += __shfl_xor(v, 1);
    v += __shfl_xor(v, 2);
    v += __shfl_xor(v, 4);
    v += __shfl_xor(v, 8);
    if (l15 == 0) lred[w][hi * 4 + j] = v;
  }
  __syncthreads();
  if (tid < 16) {
    const float l = lred[0][tid] + lred[1][tid] + lred[2][tid] + lred[3][tid];
    l_ws[(size_t)bh * TT + qg0 + tid] = l;
  }
  {
    const int b = bh >> 4, h = bh & 15;
#pragma unroll
    for (int j = 0; j < 4; ++j) {
      const int q = hi * 4 + j;
      ctxU[((size_t)b * TT + qg0 + q) * DM + h * 64 + w * 16 + l15] = acc_pv[j];
    }
  }
}

// ---------------------------------------------------------------------------
// PV partial kernel (k-split x4): grid (256 q, 4 ks), block 256.
// ---------------------------------------------------------------------------
#define PVT_S 72
__global__ __launch_bounds__(256) void pv_part_kernel(
    const bf16* __restrict__ Pws,
    const float* __restrict__ posV,
    const int* __restrict__ pos,
    float* __restrict__ PP,   // [4][256][64][64] fp32
    int slab) {
  __shared__ __align__(16) bf16 PVt[2][64 * PVT_S];
  __shared__ unsigned short possh[256];

  const int qlocal = blockIdx.x;
  const int q = slab * 256 + qlocal;
  const int ks = blockIdx.y;
  const int kbase = ks * 256;
  const int tid = threadIdx.x;
  const int w = tid >> 6, lane = tid & 63, l15 = lane & 15, hi = lane >> 4;

  possh[tid] = (unsigned short)pos[(size_t)q * TT + kbase + tid];
  __syncthreads();

  f32x4 acc[4] = {{0.f, 0.f, 0.f, 0.f}, {0.f, 0.f, 0.f, 0.f},
                  {0.f, 0.f, 0.f, 0.f}, {0.f, 0.f, 0.f, 0.f}};
  const bf16* Prow = Pws + ((size_t)qlocal * 64 + w * 16 + l15) * TT;

  for (int it = 0; it < 4; ++it) {
    const int k0 = kbase + it * 64;
    bf16* pvt = &PVt[it & 1][0];
    {
      const int kr = lane;
      const int dc = w * 16;
      const int p = possh[it * 64 + kr];
      const float* src = posV + (size_t)p * 64 + dc;
#pragma unroll
      for (int ii = 0; ii < 16; ii += 4) {
        const f32x4 v = *(const f32x4*)(src + ii);
        pvt[(dc + ii + 0) * PVT_S + kr] = __float2bfloat16(v[0]);
        pvt[(dc + ii + 1) * PVT_S + kr] = __float2bfloat16(v[1]);
        pvt[(dc + ii + 2) * PVT_S + kr] = __float2bfloat16(v[2]);
        pvt[(dc + ii + 3) * PVT_S + kr] = __float2bfloat16(v[3]);
      }
    }
    __syncthreads();
#pragma unroll
    for (int kc = 0; kc < 2; ++kc) {
      const short8 a = *(const short8*)(Prow + k0 + kc * 32 + hi * 8);
#pragma unroll
      for (int nt = 0; nt < 4; ++nt) {
        const short8 bv =
            *(const short8*)(pvt + (nt * 16 + l15) * PVT_S + kc * 32 + hi * 8);
        acc[nt] = mfma16(a, bv, acc[nt]);
      }
    }
  }

  const int bh0 = w * 16 + hi * 4;
#pragma unroll
  for (int j = 0; j < 4; ++j) {
    const int bh = bh0 + j;
    float* o = PP + (((size_t)ks * 256 + qlocal) * 64 + bh) * 64;
#pragma unroll
    for (int nt = 0; nt < 4; ++nt) o[nt * 16 + l15] = acc[nt][j];
  }
}

// ---------------------------------------------------------------------------
// Normalize: ctxB = (ctxU + sum_ks PP) / l. grid 1024, block 256.
// ---------------------------------------------------------------------------
__global__ __launch_bounds__(256) void norm_kernel(
    const float* __restrict__ PP,
    const float* __restrict__ ctxU,
    const float* __restrict__ l_ws,
    bf16* __restrict__ ctxB,
    int slab) {
  const int i4 = blockIdx.x * 256 + threadIdx.x;  // 0..262143
  const int e0 = i4 * 4;
  const int dm = e0 & 1023;
  const int qlocal = (e0 >> 10) & 255;
  const int b = e0 >> 18;
  const int h = dm >> 6, d0 = dm & 63;
  const int bh = b * 16 + h;
  const int q = slab * 256 + qlocal;

  f32x4 v = *(const f32x4*)(ctxU + ((size_t)b * TT + q) * DM + dm);
#pragma unroll
  for (int ks = 0; ks < 4; ++ks)
    v += *(const f32x4*)(PP + (((size_t)ks * 256 + qlocal) * 64 + bh) * 64 + d0);
  const float invl = 1.0f / l_ws[(size_t)bh * TT + q];
  bf16 o[4];
#pragma unroll
  for (int j = 0; j < 4; ++j) o[j] = __float2bfloat16(v[j] * invl);
  *(short4v*)(ctxB + ((size_t)b * TT + q) * DM + dm) = *(const short4v*)o;
}

// ---------------------------------------------------------------------------
// Output projection: 128x128 LDS-tiled MFMA GEMM, BK=64, 4 waves (2x2).
// grid (8 nblk, 32 mblk), block 256.
// ---------------------------------------------------------------------------
__global__ __launch_bounds__(256) void outproj_mfma_kernel(
    const bf16* __restrict__ A,   // [4096][1024] bf16
    const bf16* __restrict__ Bt,  // [1024 n][1024 k] bf16
    float* __restrict__ C) {
  __shared__ __align__(16) bf16 As[128 * 72];
  __shared__ __align__(16) bf16 Bs[128 * 72];
  const int n0 = blockIdx.x * 128;
  const int m0 = blockIdx.y * 128;
  const int tid = threadIdx.x;
  const int w = tid >> 6, lane = tid & 63, l15 = lane & 15, hi = lane >> 4;
  const int wm = w >> 1, wn = w & 1;

  f32x4 acc[4][4];
#pragma unroll
  for (int i = 0; i < 4; ++i)
#pragma unroll
    for (int j = 0; j < 4; ++j) acc[i][j] = (f32x4){0.f, 0.f, 0.f, 0.f};

  const int sr = tid >> 1, sc = (tid & 1) * 32;
  for (int k0 = 0; k0 < 1024; k0 += 64) {
    __syncthreads();
    {
      const bf16* as = A + (size_t)(m0 + sr) * 1024 + k0 + sc;
      const bf16* bs = Bt + (size_t)(n0 + sr) * 1024 + k0 + sc;
#pragma unroll
      for (int ii = 0; ii < 32; ii += 8) {
        *(short8*)(As + sr * 72 + sc + ii) = *(const short8*)(as + ii);
        *(short8*)(Bs + sr * 72 + sc + ii) = *(const short8*)(bs + ii);
      }
    }
    __syncthreads();
#pragma unroll
    for (int kc = 0; kc < 2; ++kc) {
      short8 a[4], b[4];
#pragma unroll
      for (int i = 0; i < 4; ++i)
        a[i] = *(const short8*)(As + (wm * 64 + i * 16 + l15) * 72 + kc * 32 +
                                hi * 8);
#pragma unroll
      for (int j = 0; j < 4; ++j)
        b[j] = *(const short8*)(Bs + (wn * 64 + j * 16 + l15) * 72 + kc * 32 +
                                hi * 8);
#pragma unroll
      for (int i = 0; i < 4; ++i)
#pragma unroll
        for (int j = 0; j < 4; ++j) acc[i][j] = mfma16(a[i], b[j], acc[i][j]);
    }
  }
#pragma unroll
  for (int i = 0; i < 4; ++i) {
#pragma unroll
    for (int jj = 0; jj < 4; ++jj) {
      const size_t row = (size_t)(m0 + wm * 64 + i * 16 + hi * 4 + jj) * 1024;
#pragma unroll
      for (int j = 0; j < 4; ++j)
        C[row + n0 + wn * 64 + j * 16 + l15] = acc[i][j][jj];
    }
  }
}

// ---------------------------------------------------------------------------
extern "C" void kernel_launch(void* const* d_in, const int* in_sizes, int n_in,
                              void* d_out, int out_size, void* d_ws,
                              size_t ws_size, hipStream_t stream) {
  const float* x = (const float*)d_in[0];
  const float* WQ = (const float*)d_in[1];
  const float* WK = (const float*)d_in[2];
  const float* WV = (const float*)d_in[3];
  const float* WZ = (const float*)d_in[4];
  const float* posK = (const float*)d_in[5];
  const float* posV = (const float*)d_in[6];
  const float* maskp = (const float*)d_in[7];
  const int* pos = (const int*)d_in[8];
  float* out = (float*)d_out;

  char* p = (char*)d_ws;
  bf16* Qb = (bf16*)p;        p += (size_t)64 * 1024 * 64 * 2;   // 8 MB
  bf16* Kb = (bf16*)p;        p += (size_t)64 * 1024 * 64 * 2;   // 8 MB
  bf16* Vb = (bf16*)p;        p += (size_t)64 * 1024 * 64 * 2;   // 8 MB
  bf16* Vt = (bf16*)p;        p += (size_t)64 * 64 * 1024 * 2;   // 8 MB
  bf16* posKbf = (bf16*)p;    p += (size_t)2048 * 64 * 2;        // 256 KB
  bf16* WzT = (bf16*)p;       p += (size_t)1024 * 1024 * 2;      // 2 MB
  bf16* Pws = (bf16*)p;       p += (size_t)256 * 64 * 1024 * 2;  // 32 MB
  float* l_ws = (float*)p;    p += (size_t)64 * 1024 * 4;        // 256 KB
  float* ctxU = (float*)p;    p += (size_t)4 * 1024 * 1024 * 4;  // 16 MB
  bf16* ctxB = (bf16*)p;      p += (size_t)4 * 1024 * 1024 * 2;  // 8 MB
  float* PP = (float*)p;      p += (size_t)4 * 256 * 64 * 64 * 4; // 16 MB

  // Aliases (dead-range reuse, safe under stream ordering):
  bf16* xb = (bf16*)ctxU;  // xb dead after qkv; ctxU written later
  bf16* Wt = ctxB;         // Wt dead after qkv; ctxB written later

  xb_kernel<<<2048, 256, 0, stream>>>(x, xb);
  prep_w_kernel<<<dim3(16, 3), 256, 0, stream>>>(WQ, WK, WV, Wt);
  prep_posk_kernel<<<512, 256, 0, stream>>>(posK, posKbf);
  trans_wz_kernel<<<dim3(16, 16), 256, 0, stream>>>(WZ, WzT);
  qkv_mfma_kernel<<<dim3(16, 64), 256, 0, stream>>>(xb, Wt, Qb, Kb, Vb);
  trans_v_kernel<<<dim3(16, 64), 256, 0, stream>>>(Vb, Vt);

  for (int slab = 0; slab < 4; ++slab) {
    score_pv_kernel<<<dim3(64, 16), 256, 0, stream>>>(
        Qb, Kb, posKbf, Vt, maskp, pos, Pws, l_ws, ctxU, slab);
    pv_part_kernel<<<dim3(256, 4), 256, 0, stream>>>(Pws, posV, pos, PP, slab);
    norm_kernel<<<1024, 256, 0, stream>>>(PP, ctxU, l_ws, ctxB, slab);
  }
  outproj_mfma_kernel<<<dim3(8, 32), 256, 0, stream>>>(ctxB, WzT, out);
}